// Round 5
// baseline (1267.841 us; speedup 1.0000x reference)
//
#include <hip/hip_runtime.h>

// ---------------------------------------------------------------------------
// NeuralCA fused step, multi-launch, 4 waves/SIMD:
//   512-thread blocks (8 waves), 2-row blocks, 448 blocks, 2 blocks/CU
//   (63.8 KB LDS), __launch_bounds__(512,4) -> VGPR cap 128/wave.
//   waves 0-3 (G1, quarter wq): h1 chans 32wq..32wq+31 of tiles {2j,2j+1}
//   waves 4-7 (G23, quarter g): G2 chans 32g..+31 of tiles {2(j-1),2(j-1)+1};
//        waves g<2 also: G3 full-K + epilogue of tile 2(j-2)+g
//
//   R12 (on R11): BARRIERS REPLACED BY MAILBOX FLAGS (producer-consumer).
//   Evidence: R8 (fewer LDS reads) worse, R9 (VMEM+setprio) neutral, R11
//   (conflict-free writes) only -2% -> no pipe is saturated; the 16-iter
//   lockstep (post-barrier read bursts + lgkm drain + skew, ~1300 cyc/iter)
//   is the structural cost. sXH is static after the prologue sync, so the
//   only cross-wave deps are h1/h2 handoffs -> per-slot fill/free counters
//   in LDS. G1 free-runs up to 2 iters ahead; read bursts self-spread.
//   Protocol: producer waits slot-free, writes, lgkmcnt(0), bumps fill;
//   consumer waits fill, reads, MFMAs, bumps free. LDS pipe is in-order
//   per wave + lgkmcnt(0) before every bump => no data races.
//   Targets (verified j=0..15 incl tails):
//     G1  write j (j>=2): h1_free[j&1]  >= 4*(j>>1)
//     G2  read  j:        h1_fill[s=(j-1)&1] >= 4*(((j-1)>>1)+1)
//     G2  write j (j>=3): h2_free[j&1]  >= 2*((j-(2-(j&1)))>>1)
//     G3  read  j (i=j-1): h2_fill[i&1] >= 4*(((i-(2-(i&1)))>>1)+1)
// ---------------------------------------------------------------------------

typedef __attribute__((ext_vector_type(8))) short short8;
typedef __attribute__((ext_vector_type(4))) float float4v;
typedef __attribute__((ext_vector_type(2))) unsigned int uint2v;

#define MFMA16(a, b, c) __builtin_amdgcn_mfma_f32_16x16x32_bf16((a), (b), (c), 0, 0, 0)

__device__ __forceinline__ short f2bf(float f) {
  unsigned u = __builtin_bit_cast(unsigned, f);
  return (short)((u + 0x8000u) >> 16);     // round-half-up
}

__device__ __forceinline__ unsigned pk2bf(float a, float b) {
#if __has_builtin(__builtin_amdgcn_cvt_pk_bf16_f32)
  typedef __attribute__((ext_vector_type(2))) __bf16 bf2;
  bf2 r = __builtin_amdgcn_cvt_pk_bf16_f32(a, b);
  return __builtin_bit_cast(unsigned, r);
#else
  unsigned ua = __builtin_bit_cast(unsigned, a), ub = __builtin_bit_cast(unsigned, b);
  return ((ua + 0x8000u) >> 16) | (((ub + 0x8000u) >> 16) << 16);
#endif
}

__device__ __forceinline__ void async16(const void* g, void* l) {
  __builtin_amdgcn_global_load_lds((const __attribute__((address_space(1))) void*)g,
                                   (__attribute__((address_space(3))) void*)l,
                                   16, 0, 0);
}

// spin until *f >= target (broadcast ds_read; all lanes poll, reconverge)
__device__ __forceinline__ void wait_flag(const volatile unsigned* f, unsigned target) {
  while (*f < target) __builtin_amdgcn_s_sleep(1);
  __builtin_amdgcn_sched_barrier(0);
  asm volatile("" ::: "memory");           // no LDS op crosses above this
}

// drain own LDS writes, then bump the counter (one lane)
__device__ __forceinline__ void bump_flag(unsigned* f, int lane) {
  asm volatile("s_waitcnt lgkmcnt(0)" ::: "memory");
  if (lane == 0) atomicAdd(f, 1u);
}

// ---- workspace layout (bytes) ----
#define WS_WE    0          // W_eff^T [128][168] bf16 (K pad 144->168, zeros)
#define WS_W2    43008      // W2      [128][136] bf16 (K identity, pad 136)
#define WS_W3    77824      // W3      [ 16][136] bf16 (identity, pad 2560)
#define WS_B1    82944      // b1 f32 [128] (identity)
#define WS_B2    83456      // b2 f32 [128] (identity)
#define WS_X32A  83968
#define WS_X32B  12929024
#define WS_X16A  25774080
#define WS_X16B  32196608

// ---------------------------------------------------------------------------
__global__ void prep_x(const float* __restrict__ x, float* __restrict__ x32,
                       short* __restrict__ x16) {
  int i = blockIdx.x * 256 + threadIdx.x;          // exactly 3211264 threads
  int w = i % 224;
  int h = (i / 224) % 224;
  int c = (i / 50176) & 15;
  int bb = i / 802816;
  float v = x[i];
  int o = ((bb * 224 + h) * 224 + w) * 16 + c;     // NHWC
  x32[o] = v;
  x16[o] = f2bf(v);
}

// identity layouts (operand-swapped mailboxes store chpos == channel)
__global__ void prep_w(const float* __restrict__ wp, const float* __restrict__ w1,
                       const float* __restrict__ b1, const float* __restrict__ w2,
                       const float* __restrict__ b2, const float* __restrict__ w3,
                       short* __restrict__ wE, short* __restrict__ w2t,
                       short* __restrict__ w3t, float* __restrict__ b1p,
                       float* __restrict__ b2p) {
  int i = blockIdx.x * 256 + threadIdx.x;          // exactly 41728 threads
  if (i < 21504) {                                  // W_eff [o=128][k=168]
    int o = i / 168, k = i % 168;
    float v = 0.f;
    if (k < 144) {
      int off = k >> 4, c = k & 15;                 // k = offset*16 + c
      for (int c3 = 0; c3 < 48; ++c3)
        v += w1[o * 48 + c3] * wp[c3 * 144 + c * 9 + off];
    }
    wE[i] = f2bf(v);
  } else if (i < 38912) {                           // W2 [n=128][kk=136]
    int j = i - 21504;
    int n = j / 136, kk = j % 136;
    w2t[j] = (kk < 128) ? f2bf(w2[n * 128 + kk]) : (short)0;
  } else if (i < 41472) {                           // W3 [16][136], pad 2560
    int j = i - 38912;
    float v = 0.f;
    if (j < 2176) {
      int n = j / 136, kk = j % 136;
      if (kk < 128) v = w3[n * 128 + kk];
    }
    w3t[j] = f2bf(v);
  } else if (i < 41600) {
    int p = i - 41472;
    b1p[p] = b1[p];
  } else {
    int p = i - 41600;
    b2p[p] = b2[p];
  }
}

// ---------------------------------------------------------------------------
// One CA step. Block = 2 image rows, 512 threads = 8 waves. 28 tiles of
// 16 px; flag-decoupled pipeline:
//   G1 wave wq:  j=0..13:  chan-quarter of h1, tiles {2j,2j+1} -> sBUF j&1
//   G23 wave g:  j=1..14:  chan-quarter of h2, tiles {2(j-1),..} -> sH2 j&1
//   G23 g<2:     j=2..15:  G3 full-K + epilogue, tile 2(j-2)+g
template <bool LAST>
__global__ __launch_bounds__(512, 4) void ca_step(
    const short* __restrict__ wEg, const short* __restrict__ w2g,
    const short* __restrict__ w3g, const float* __restrict__ b1p,
    const float* __restrict__ b2p, const float* __restrict__ xs32,
    const short* __restrict__ xs16, float* __restrict__ xd32,
    short* __restrict__ xd16, float* __restrict__ dout) {
  __shared__ short sXH[4 * 3616];       // 28928 B  halo: 4 rows x 226 x 16ch
  __shared__ short sBUF[2 * 2 * 2176];  // 17408 B  h1 mailbox dbuf x 2 tiles
  __shared__ short sH2[2 * 2 * 2176];   // 17408 B  h2 dbuf x 2 tiles
  __shared__ unsigned sFLAG[8];         // 0,1 h1fill | 2,3 h1free | 4,5 h2fill | 6,7 h2free
  // total 63776 B -> 2 blocks/CU, 16 waves/CU = 4 waves/SIMD

  const int tid = threadIdx.x;
  const int lane = tid & 63;
  const int wv = tid >> 6;              // 0..7
  const int c16 = lane & 15;
  const int q = lane >> 4;
  const int q8 = q * 8;
  const int qh = q >> 1;
  const int c0 = (q & 1) * 8;

  const int blk = blockIdx.x;           // 448 = 4 batches x 112 rowgroups
  const int b = blk / 112;
  const int h0 = (blk % 112) * 2;

  if (tid < 8) sFLAG[tid] = 0;

  // ---- stage halo: 4 rows x 7 chunks (1KB each); OOB rows -> zeros ----
  const short8 z8 = {0, 0, 0, 0, 0, 0, 0, 0};
  for (int t = wv; t < 28; t += 8) {
    int hr = t / 7, ck = t % 7;
    int hh = h0 - 1 + hr;
    char* l = (char*)sXH + hr * 7232 + 32 + ck * 1024;  // col 0 = image col -1
    if (hh >= 0 && hh < 224) {
      const char* g = (const char*)xs16 + ((size_t)(b * 224 + hh) * 224) * 32 + ck * 1024;
      async16(g + lane * 16, l);
    } else {
      *(short8*)(l + lane * 16) = z8;
    }
  }
  if (tid < 16) {   // zero edge columns (image col -1 and 224) for all 4 rows
    int hr = tid >> 2, wch = tid & 3;
    int colb = (wch < 2) ? 0 : 225;
    *(short8*)((char*)sXH + hr * 7232 + colb * 32 + (wch & 1) * 16) = z8;
  }

  if (wv < 4) {
    // ====== G1 role, chan-quarter wq: conv3x3+MLP1 fused (A=W, B=x) ======
    const int wq = wv;
    const int obase = 32 * wq;          // channel rows 32wq..32wq+31
    short8 wf[5][2];                    // 40 VGPR; A-frag: row obase+16n+c16
#pragma unroll
    for (int kc = 0; kc < 5; ++kc)
#pragma unroll
      for (int n = 0; n < 2; ++n)
        wf[kc][n] = *(const short8*)(wEg + (obase + 16 * n + c16) * 168 + kc * 32 + q8);
    float4v bH[2];                      // bias for chans obase+16n+4q..+3
#pragma unroll
    for (int n = 0; n < 2; ++n)
      bH[n] = *(const float4v*)(b1p + obase + 16 * n + 4 * q);

    __syncthreads();                    // halo + flags ready (drains vmcnt)

    for (int j = 0; j < 14; ++j) {
      const int t0 = 2 * j, t1 = t0 + 1;
      const int hb0 = ((t0 / 14) * 226 + (t0 % 14) * 16) * 16;
      const int hb1 = ((t1 / 14) * 226 + (t1 % 14) * 16) * 16;
      float4v acc[2][2];
#pragma unroll
      for (int tt = 0; tt < 2; ++tt)
#pragma unroll
        for (int n = 0; n < 2; ++n) acc[tt][n] = (float4v){0.f, 0.f, 0.f, 0.f};
      __builtin_amdgcn_s_setprio(1);
#pragma unroll
      for (int kc = 0; kc < 5; ++kc) {
        int off = kc * 2 + qh;
        if (off > 8) off = 8;           // K 144..159 hit zero rows of W_eff
        int dy = (off * 11) >> 5;       // off/3
        int dxx = off - dy * 3;
        const int ao = (dy * 226 + dxx + c16) * 16 + c0;
        short8 a0 = *(const short8*)(sXH + hb0 + ao);   // B-frag (static sXH)
        short8 a1 = *(const short8*)(sXH + hb1 + ao);
#pragma unroll
        for (int n = 0; n < 2; ++n) {
          acc[0][n] = MFMA16(wf[kc][n], a0, acc[0][n]);
          acc[1][n] = MFMA16(wf[kc][n], a1, acc[1][n]);
        }
      }
      __builtin_amdgcn_s_setprio(0);
      // slot must be free (G2's read of fill j-2 done) before overwrite
      if (j >= 2) wait_flag(&sFLAG[2 + (j & 1)], 4u * (unsigned)(j >> 1));
      // D[ch][px]: lane=px(c16), regs=4 consecutive ch -> b64 writes
#pragma unroll
      for (int tt = 0; tt < 2; ++tt) {
        short* dst = sBUF + ((j & 1) * 2 + tt) * 2176 + c16 * 136;
#pragma unroll
        for (int n = 0; n < 2; ++n) {
          unsigned d0 = pk2bf(fmaxf(acc[tt][n][0] + bH[n][0], 0.f),
                              fmaxf(acc[tt][n][1] + bH[n][1], 0.f));
          unsigned d1 = pk2bf(fmaxf(acc[tt][n][2] + bH[n][2], 0.f),
                              fmaxf(acc[tt][n][3] + bH[n][3], 0.f));
          *(uint2v*)(dst + obase + 16 * n + 4 * q) = (uint2v){d0, d1};
        }
      }
      bump_flag(&sFLAG[0 + (j & 1)], lane);   // lgkmcnt(0) then fill++
    }
  } else {
    // ====== G23 role, chan-quarter g: MLP2 (A=W2, B=h1) + (g<2) MLP3 =====
    const int g = wv - 4;
    const int obase = 32 * g;
    short8 w2f[4][2];                   // 32 VGPR; A-frag row obase+16n+c16
    short8 w3f[4];                      // 16 VGPR
#pragma unroll
    for (int kc = 0; kc < 4; ++kc)
#pragma unroll
      for (int n = 0; n < 2; ++n)
        w2f[kc][n] = *(const short8*)(w2g + (obase + 16 * n + c16) * 136 + kc * 32 + q8);
#pragma unroll
    for (int kc = 0; kc < 4; ++kc)
      w3f[kc] = *(const short8*)(w3g + c16 * 136 + kc * 32 + q8);
    float4v bG[2];
#pragma unroll
    for (int n = 0; n < 2; ++n)
      bG[n] = *(const float4v*)(b2p + obase + 16 * n + 4 * q);

    __syncthreads();                    // halo + flags ready

    for (int j = 0; j < 16; ++j) {
      float4v acc3;
      int cb3 = 0, hglob3 = 0;
      const bool doG3 = (g < 2) && (j >= 2);
      if (doG3) {                       // residual (b128) -> MFMA C-in
        const int t3 = 2 * (j - 2) + g;
        cb3 = (t3 % 14) * 16; hglob3 = h0 + t3 / 14;
        const size_t pix = (size_t)(b * 224 + hglob3) * 224 + cb3 + c16;
        acc3 = *(const float4v*)(xs32 + pix * 16 + q * 4);
      }
      if (j >= 1 && j <= 14) {          // G2 quarter on tiles 2(j-1), 2(j-1)+1
        const int s1 = (j - 1) & 1;
        wait_flag(&sFLAG[0 + s1], 4u * (unsigned)(((j - 1) >> 1) + 1));
        const short* srcA = sBUF + (s1 * 2 + 0) * 2176;
        const short* srcB = sBUF + (s1 * 2 + 1) * 2176;
        float4v acc2[2][2];
#pragma unroll
        for (int tt = 0; tt < 2; ++tt)
#pragma unroll
          for (int n = 0; n < 2; ++n) acc2[tt][n] = (float4v){0.f, 0.f, 0.f, 0.f};
        __builtin_amdgcn_s_setprio(1);
#pragma unroll
        for (int kc = 0; kc < 4; ++kc) {
          short8 aA = *(const short8*)(srcA + c16 * 136 + kc * 32 + q8);  // B-frag
          short8 aB = *(const short8*)(srcB + c16 * 136 + kc * 32 + q8);
#pragma unroll
          for (int n = 0; n < 2; ++n) {
            acc2[0][n] = MFMA16(w2f[kc][n], aA, acc2[0][n]);
            acc2[1][n] = MFMA16(w2f[kc][n], aB, acc2[1][n]);
          }
        }
        __builtin_amdgcn_s_setprio(0);
        bump_flag(&sFLAG[2 + s1], lane);        // h1 slot consumed
        // h2 slot must be free (G3's read of fill j-2 done)
        if (j >= 3) wait_flag(&sFLAG[6 + (j & 1)],
                              2u * (unsigned)((j - (2 - (j & 1))) >> 1));
        // D[ch2][px] -> b64 writes, conflict-free
#pragma unroll
        for (int tt = 0; tt < 2; ++tt) {
          short* dsth2 = sH2 + ((j & 1) * 2 + tt) * 2176 + c16 * 136;
#pragma unroll
          for (int n = 0; n < 2; ++n) {
            unsigned d0 = pk2bf(fmaxf(acc2[tt][n][0] + bG[n][0], 0.f),
                                fmaxf(acc2[tt][n][1] + bG[n][1], 0.f));
            unsigned d1 = pk2bf(fmaxf(acc2[tt][n][2] + bG[n][2], 0.f),
                                fmaxf(acc2[tt][n][3] + bG[n][3], 0.f));
            *(uint2v*)(dsth2 + obase + 16 * n + 4 * q) = (uint2v){d0, d1};
          }
        }
        bump_flag(&sFLAG[4 + (j & 1)], lane);   // lgkmcnt(0) then h2 fill++
      }
      if (doG3) {                       // G3 full-K + epilogue, tile 2(j-2)+g
        const int i = j - 1;
        const int s2 = i & 1;
        wait_flag(&sFLAG[4 + s2],
                  4u * (unsigned)(((i - (2 - s2)) >> 1) + 1));
        // A=w3f, B=h2frag: D[ch][px], lane=px(c16), regs=4 consecutive ch
        const short* srch2 = sH2 + (s2 * 2 + g) * 2176;
        __builtin_amdgcn_s_setprio(1);
#pragma unroll
        for (int kc = 0; kc < 4; ++kc) {
          short8 a = *(const short8*)(srch2 + c16 * 136 + kc * 32 + q8);
          acc3 = MFMA16(w3f[kc], a, acc3);
        }
        __builtin_amdgcn_s_setprio(0);
        bump_flag(&sFLAG[6 + s2], lane);        // h2 slot consumed
        float4v vv;
#pragma unroll
        for (int r = 0; r < 4; ++r) vv[r] = fminf(fmaxf(acc3[r], 0.f), 1.f);
        if (LAST) {
#pragma unroll
          for (int r = 0; r < 4; ++r)
            dout[((size_t)(b * 16 + q * 4 + r) * 224 + hglob3) * 224 + cb3 + c16] = vv[r];
        } else {
          const size_t pix = (size_t)(b * 224 + hglob3) * 224 + cb3 + c16;
          *(float4v*)(xd32 + pix * 16 + q * 4) = vv;          // 1x b128
          *(uint2v*)(xd16 + pix * 16 + q * 4) =               // 1x b64
              (uint2v){pk2bf(vv[0], vv[1]), pk2bf(vv[2], vv[3])};
        }
      }
    }
  }
}

// ---------------------------------------------------------------------------
extern "C" void kernel_launch(void* const* d_in, const int* in_sizes, int n_in,
                              void* d_out, int out_size, void* d_ws, size_t ws_size,
                              hipStream_t stream) {
  const float* x  = (const float*)d_in[0];
  const float* wp = (const float*)d_in[1];
  const float* w1 = (const float*)d_in[2];
  const float* b1 = (const float*)d_in[3];
  const float* w2 = (const float*)d_in[4];
  const float* b2 = (const float*)d_in[5];
  const float* w3 = (const float*)d_in[6];

  char* ws = (char*)d_ws;
  short* wEg = (short*)(ws + WS_WE);
  short* w2g = (short*)(ws + WS_W2);
  short* w3g = (short*)(ws + WS_W3);
  float* b1p = (float*)(ws + WS_B1);
  float* b2p = (float*)(ws + WS_B2);
  float* X32[2] = {(float*)(ws + WS_X32A), (float*)(ws + WS_X32B)};
  short* X16[2] = {(short*)(ws + WS_X16A), (short*)(ws + WS_X16B)};

  prep_x<<<12544, 256, 0, stream>>>(x, X32[0], X16[0]);
  prep_w<<<163, 256, 0, stream>>>(wp, w1, b1, w2, b2, w3, wEg, w2g, w3g, b1p, b2p);

  for (int s = 0; s < 39; ++s) {
    int sb = s & 1;
    ca_step<false><<<448, 512, 0, stream>>>(wEg, w2g, w3g, b1p, b2p,
                                            X32[sb], X16[sb],
                                            X32[1 - sb], X16[1 - sb], nullptr);
  }
  ca_step<true><<<448, 512, 0, stream>>>(wEg, w2g, w3g, b1p, b2p,
                                         X32[1], X16[1],
                                         X32[0], X16[0], (float*)d_out);
}

// Round 6
// 1018.240 us; speedup vs baseline: 1.2451x; 1.2451x over previous
//
#include <hip/hip_runtime.h>

// ---------------------------------------------------------------------------
// NeuralCA fused step, multi-launch, 4 waves/SIMD:
//   512-thread blocks (8 waves), 2-row blocks, 448 blocks, 2 blocks/CU
//   (63.7 KB LDS), __launch_bounds__(512,4) -> VGPR cap 128/wave.
//   waves 0-3 (G1, quarter wq): h1 chans 32wq..32wq+31 of tiles {2j,2j+1}
//   waves 4-7 (G23): G2 on tiles {2(j-1),2(j-1)+1} with ASYMMETRIC channel
//        split 16/16/48/48 (g=0,1 light; g=2,3 heavy); g<2 also: G3 full-K
//        + epilogue of tile 2(j-2)+g.
//   h1/h2 via double-buffered LDS mailboxes, 1 lgkm-only barrier per iter.
//
//   R13 (on R11; R12 flag-sync REVERTED: +28%, software sync >> s_barrier):
//   - Evidence chain: R8 fewer-reads worse, R9 VMEM+setprio neutral, R11
//     conflict-free writes -2%, R12 flags +28% -> no pipe saturated; cost
//     is barrier SKEW set by the heaviest wave class (old g<2: G2 16 MFMA
//     + G3 + epilogue). Fix: rebalance, not restructure.
//   - G2 split 48/48/16/16: G3-duty waves (g<2) compute only 16 h2 chans
//     (8 MFMA), free waves compute 48 (24 MFMA). Totals unchanged.
//   - XCD-bijective swizzle (448=8x56): same row-band -> same XCD L2 across
//     the 40 launches; step s writes are step s+1 reads.
// ---------------------------------------------------------------------------

typedef __attribute__((ext_vector_type(8))) short short8;
typedef __attribute__((ext_vector_type(4))) float float4v;
typedef __attribute__((ext_vector_type(2))) unsigned int uint2v;

#define MFMA16(a, b, c) __builtin_amdgcn_mfma_f32_16x16x32_bf16((a), (b), (c), 0, 0, 0)

__device__ __forceinline__ short f2bf(float f) {
  unsigned u = __builtin_bit_cast(unsigned, f);
  return (short)((u + 0x8000u) >> 16);     // round-half-up
}

__device__ __forceinline__ unsigned pk2bf(float a, float b) {
#if __has_builtin(__builtin_amdgcn_cvt_pk_bf16_f32)
  typedef __attribute__((ext_vector_type(2))) __bf16 bf2;
  bf2 r = __builtin_amdgcn_cvt_pk_bf16_f32(a, b);
  return __builtin_bit_cast(unsigned, r);
#else
  unsigned ua = __builtin_bit_cast(unsigned, a), ub = __builtin_bit_cast(unsigned, b);
  return ((ua + 0x8000u) >> 16) | (((ub + 0x8000u) >> 16) << 16);
#endif
}

__device__ __forceinline__ void async16(const void* g, void* l) {
  __builtin_amdgcn_global_load_lds((const __attribute__((address_space(1))) void*)g,
                                   (__attribute__((address_space(3))) void*)l,
                                   16, 0, 0);
}

// LDS-only barrier (no vmcnt drain - global stores fly free)
__device__ __forceinline__ void sync_lds() {
  asm volatile("s_waitcnt lgkmcnt(0)\n\ts_barrier" ::: "memory");
}

// ---- workspace layout (bytes) ----
#define WS_WE    0          // W_eff^T [128][168] bf16 (K pad 144->168, zeros)
#define WS_W2    43008      // W2      [128][136] bf16 (K identity, pad 136)
#define WS_W3    77824      // W3      [ 16][136] bf16 (identity, pad 2560)
#define WS_B1    82944      // b1 f32 [128] (identity)
#define WS_B2    83456      // b2 f32 [128] (identity)
#define WS_X32A  83968
#define WS_X32B  12929024
#define WS_X16A  25774080
#define WS_X16B  32196608

// ---------------------------------------------------------------------------
__global__ void prep_x(const float* __restrict__ x, float* __restrict__ x32,
                       short* __restrict__ x16) {
  int i = blockIdx.x * 256 + threadIdx.x;          // exactly 3211264 threads
  int w = i % 224;
  int h = (i / 224) % 224;
  int c = (i / 50176) & 15;
  int bb = i / 802816;
  float v = x[i];
  int o = ((bb * 224 + h) * 224 + w) * 16 + c;     // NHWC
  x32[o] = v;
  x16[o] = f2bf(v);
}

// identity layouts (operand-swapped mailboxes store chpos == channel)
__global__ void prep_w(const float* __restrict__ wp, const float* __restrict__ w1,
                       const float* __restrict__ b1, const float* __restrict__ w2,
                       const float* __restrict__ b2, const float* __restrict__ w3,
                       short* __restrict__ wE, short* __restrict__ w2t,
                       short* __restrict__ w3t, float* __restrict__ b1p,
                       float* __restrict__ b2p) {
  int i = blockIdx.x * 256 + threadIdx.x;          // exactly 41728 threads
  if (i < 21504) {                                  // W_eff [o=128][k=168]
    int o = i / 168, k = i % 168;
    float v = 0.f;
    if (k < 144) {
      int off = k >> 4, c = k & 15;                 // k = offset*16 + c
      for (int c3 = 0; c3 < 48; ++c3)
        v += w1[o * 48 + c3] * wp[c3 * 144 + c * 9 + off];
    }
    wE[i] = f2bf(v);
  } else if (i < 38912) {                           // W2 [n=128][kk=136]
    int j = i - 21504;
    int n = j / 136, kk = j % 136;
    w2t[j] = (kk < 128) ? f2bf(w2[n * 128 + kk]) : (short)0;
  } else if (i < 41472) {                           // W3 [16][136], pad 2560
    int j = i - 38912;
    float v = 0.f;
    if (j < 2176) {
      int n = j / 136, kk = j % 136;
      if (kk < 128) v = w3[n * 128 + kk];
    }
    w3t[j] = f2bf(v);
  } else if (i < 41600) {
    int p = i - 41472;
    b1p[p] = b1[p];
  } else {
    int p = i - 41600;
    b2p[p] = b2[p];
  }
}

// ---------------------------------------------------------------------------
// One CA step. Block = 2 image rows, 512 threads = 8 waves. 28 tiles of
// 16 px; pipeline over 16 iterations:
//   G1 wave wq:  iter j<14:     chan-quarter of h1, tiles {2j,2j+1} -> sBUF j&1
//   G23 wave g:  iter 1<=j<=14: chan-slice of h2, tiles {2(j-1),..} -> sH2 j&1
//   G23 g<2:     iter j>=2:     G3 full-K + epilogue, tile 2(j-2)+g
template <bool LAST>
__global__ __launch_bounds__(512, 4) void ca_step(
    const short* __restrict__ wEg, const short* __restrict__ w2g,
    const short* __restrict__ w3g, const float* __restrict__ b1p,
    const float* __restrict__ b2p, const float* __restrict__ xs32,
    const short* __restrict__ xs16, float* __restrict__ xd32,
    short* __restrict__ xd16, float* __restrict__ dout) {
  __shared__ short sXH[4 * 3616];       // 28928 B  halo: 4 rows x 226 x 16ch
  __shared__ short sBUF[2 * 2 * 2176];  // 17408 B  h1 mailbox dbuf x 2 tiles
  __shared__ short sH2[2 * 2 * 2176];   // 17408 B  h2 dbuf x 2 tiles
  // total 63744 B -> 2 blocks/CU, 16 waves/CU = 4 waves/SIMD

  const int tid = threadIdx.x;
  const int lane = tid & 63;
  const int wv = tid >> 6;              // 0..7
  const int c16 = lane & 15;
  const int q = lane >> 4;
  const int q8 = q * 8;
  const int qh = q >> 1;
  const int c0 = (q & 1) * 8;

  // XCD-bijective swizzle: 448 = 8 XCDs x 56 -> same row-band lands on the
  // same XCD's L2 every launch (cross-step x32/x16 reuse).
  const int blk = (blockIdx.x & 7) * 56 + (blockIdx.x >> 3);
  const int b = blk / 112;              // 4 batches x 112 rowgroups
  const int h0 = (blk % 112) * 2;

  // ---- stage halo: 4 rows x 7 chunks (1KB each); OOB rows -> zeros ----
  const short8 z8 = {0, 0, 0, 0, 0, 0, 0, 0};
  for (int t = wv; t < 28; t += 8) {
    int hr = t / 7, ck = t % 7;
    int hh = h0 - 1 + hr;
    char* l = (char*)sXH + hr * 7232 + 32 + ck * 1024;  // col 0 = image col -1
    if (hh >= 0 && hh < 224) {
      const char* g = (const char*)xs16 + ((size_t)(b * 224 + hh) * 224) * 32 + ck * 1024;
      async16(g + lane * 16, l);
    } else {
      *(short8*)(l + lane * 16) = z8;
    }
  }
  if (tid < 16) {   // zero edge columns (image col -1 and 224) for all 4 rows
    int hr = tid >> 2, wch = tid & 3;
    int colb = (wch < 2) ? 0 : 225;
    *(short8*)((char*)sXH + hr * 7232 + colb * 32 + (wch & 1) * 16) = z8;
  }

  if (wv < 4) {
    // ====== G1 role, chan-quarter wq: conv3x3+MLP1 fused (A=W, B=x) ======
    const int wq = wv;
    const int obase = 32 * wq;          // channel rows 32wq..32wq+31
    short8 wf[5][2];                    // 40 VGPR; A-frag: row obase+16n+c16
#pragma unroll
    for (int kc = 0; kc < 5; ++kc)
#pragma unroll
      for (int n = 0; n < 2; ++n)
        wf[kc][n] = *(const short8*)(wEg + (obase + 16 * n + c16) * 168 + kc * 32 + q8);
    float4v bH[2];                      // bias for chans obase+16n+4q..+3
#pragma unroll
    for (int n = 0; n < 2; ++n)
      bH[n] = *(const float4v*)(b1p + obase + 16 * n + 4 * q);

    __syncthreads();                    // halo ready (drains vmcnt)

    for (int j = 0; j < 16; ++j) {
      if (j < 14) {
        const int t0 = 2 * j, t1 = t0 + 1;
        const int hb0 = ((t0 / 14) * 226 + (t0 % 14) * 16) * 16;
        const int hb1 = ((t1 / 14) * 226 + (t1 % 14) * 16) * 16;
        float4v acc[2][2];
#pragma unroll
        for (int tt = 0; tt < 2; ++tt)
#pragma unroll
          for (int n = 0; n < 2; ++n) acc[tt][n] = (float4v){0.f, 0.f, 0.f, 0.f};
        __builtin_amdgcn_s_setprio(1);
#pragma unroll
        for (int kc = 0; kc < 5; ++kc) {
          int off = kc * 2 + qh;
          if (off > 8) off = 8;         // K 144..159 hit zero rows of W_eff
          int dy = (off * 11) >> 5;     // off/3
          int dxx = off - dy * 3;
          const int ao = (dy * 226 + dxx + c16) * 16 + c0;
          short8 a0 = *(const short8*)(sXH + hb0 + ao);   // B-frag, same addr
          short8 a1 = *(const short8*)(sXH + hb1 + ao);
#pragma unroll
          for (int n = 0; n < 2; ++n) {
            acc[0][n] = MFMA16(wf[kc][n], a0, acc[0][n]);
            acc[1][n] = MFMA16(wf[kc][n], a1, acc[1][n]);
          }
        }
        __builtin_amdgcn_s_setprio(0);
        // D[ch][px]: lane=px(c16), regs=4 consecutive ch -> b64 writes
#pragma unroll
        for (int tt = 0; tt < 2; ++tt) {
          short* dst = sBUF + ((j & 1) * 2 + tt) * 2176 + c16 * 136;
#pragma unroll
          for (int n = 0; n < 2; ++n) {
            unsigned d0 = pk2bf(fmaxf(acc[tt][n][0] + bH[n][0], 0.f),
                                fmaxf(acc[tt][n][1] + bH[n][1], 0.f));
            unsigned d1 = pk2bf(fmaxf(acc[tt][n][2] + bH[n][2], 0.f),
                                fmaxf(acc[tt][n][3] + bH[n][3], 0.f));
            *(uint2v*)(dst + obase + 16 * n + 4 * q) = (uint2v){d0, d1};
          }
        }
      }
      sync_lds();
    }
  } else {
    // ====== G23 role: G2 asymmetric 16/16/48/48 + (g<2) G3/update ========
    const int g = wv - 4;
    const bool light = (g < 2);         // light waves also run G3 + epilogue
    const int ob2 = light ? (96 + 16 * g) : (48 * (g - 2));
    // light: 1 n-frag (16 ch, 8 MFMA); heavy: 3 n-frags (48 ch, 24 MFMA)
    short8 w2a[4];                      // frag 0 (all waves)      16 VGPR
    short8 w2b[4][2];                   // frags 1,2 (heavy only)  32 VGPR
    short8 w3f[4];                      // G3 weights (light only) 16 VGPR
#pragma unroll
    for (int kc = 0; kc < 4; ++kc)
      w2a[kc] = *(const short8*)(w2g + (ob2 + c16) * 136 + kc * 32 + q8);
    if (!light) {
#pragma unroll
      for (int kc = 0; kc < 4; ++kc)
#pragma unroll
        for (int nf = 0; nf < 2; ++nf)
          w2b[kc][nf] = *(const short8*)(w2g + (ob2 + 16 * (nf + 1) + c16) * 136 + kc * 32 + q8);
    } else {
#pragma unroll
      for (int kc = 0; kc < 4; ++kc)
        w3f[kc] = *(const short8*)(w3g + c16 * 136 + kc * 32 + q8);
    }
    float4v bG[3];
    bG[0] = *(const float4v*)(b2p + ob2 + 4 * q);
    if (!light) {
#pragma unroll
      for (int nf = 1; nf < 3; ++nf)
        bG[nf] = *(const float4v*)(b2p + ob2 + 16 * nf + 4 * q);
    }

    __syncthreads();                    // halo ready

    for (int j = 0; j < 16; ++j) {
      float4v acc3;
      int cb3 = 0, hglob3 = 0;
      const bool doG3 = light && (j >= 2);
      if (doG3) {                       // residual (b128) -> MFMA C-in
        const int t3 = 2 * (j - 2) + g;
        cb3 = (t3 % 14) * 16; hglob3 = h0 + t3 / 14;
        const size_t pix = (size_t)(b * 224 + hglob3) * 224 + cb3 + c16;
        acc3 = *(const float4v*)(xs32 + pix * 16 + q * 4);
      }
      if (j >= 1 && j <= 14) {          // G2 slice on tiles 2(j-1), 2(j-1)+1
        const short* srcA = sBUF + (((j - 1) & 1) * 2 + 0) * 2176;
        const short* srcB = sBUF + (((j - 1) & 1) * 2 + 1) * 2176;
        if (light) {
          float4v a2[2];
          a2[0] = (float4v){0.f, 0.f, 0.f, 0.f};
          a2[1] = (float4v){0.f, 0.f, 0.f, 0.f};
          __builtin_amdgcn_s_setprio(1);
#pragma unroll
          for (int kc = 0; kc < 4; ++kc) {
            short8 aA = *(const short8*)(srcA + c16 * 136 + kc * 32 + q8);
            short8 aB = *(const short8*)(srcB + c16 * 136 + kc * 32 + q8);
            a2[0] = MFMA16(w2a[kc], aA, a2[0]);
            a2[1] = MFMA16(w2a[kc], aB, a2[1]);
          }
          __builtin_amdgcn_s_setprio(0);
#pragma unroll
          for (int tt = 0; tt < 2; ++tt) {
            short* dsth2 = sH2 + ((j & 1) * 2 + tt) * 2176 + c16 * 136;
            unsigned d0 = pk2bf(fmaxf(a2[tt][0] + bG[0][0], 0.f),
                                fmaxf(a2[tt][1] + bG[0][1], 0.f));
            unsigned d1 = pk2bf(fmaxf(a2[tt][2] + bG[0][2], 0.f),
                                fmaxf(a2[tt][3] + bG[0][3], 0.f));
            *(uint2v*)(dsth2 + ob2 + 4 * q) = (uint2v){d0, d1};
          }
        } else {
          float4v a2[2][3];
#pragma unroll
          for (int tt = 0; tt < 2; ++tt)
#pragma unroll
            for (int nf = 0; nf < 3; ++nf) a2[tt][nf] = (float4v){0.f, 0.f, 0.f, 0.f};
          __builtin_amdgcn_s_setprio(1);
#pragma unroll
          for (int kc = 0; kc < 4; ++kc) {
            short8 aA = *(const short8*)(srcA + c16 * 136 + kc * 32 + q8);
            short8 aB = *(const short8*)(srcB + c16 * 136 + kc * 32 + q8);
            a2[0][0] = MFMA16(w2a[kc], aA, a2[0][0]);
            a2[1][0] = MFMA16(w2a[kc], aB, a2[1][0]);
#pragma unroll
            for (int nf = 0; nf < 2; ++nf) {
              a2[0][nf + 1] = MFMA16(w2b[kc][nf], aA, a2[0][nf + 1]);
              a2[1][nf + 1] = MFMA16(w2b[kc][nf], aB, a2[1][nf + 1]);
            }
          }
          __builtin_amdgcn_s_setprio(0);
#pragma unroll
          for (int tt = 0; tt < 2; ++tt) {
            short* dsth2 = sH2 + ((j & 1) * 2 + tt) * 2176 + c16 * 136;
#pragma unroll
            for (int nf = 0; nf < 3; ++nf) {
              unsigned d0 = pk2bf(fmaxf(a2[tt][nf][0] + bG[nf][0], 0.f),
                                  fmaxf(a2[tt][nf][1] + bG[nf][1], 0.f));
              unsigned d1 = pk2bf(fmaxf(a2[tt][nf][2] + bG[nf][2], 0.f),
                                  fmaxf(a2[tt][nf][3] + bG[nf][3], 0.f));
              *(uint2v*)(dsth2 + ob2 + 16 * nf + 4 * q) = (uint2v){d0, d1};
            }
          }
        }
      }
      if (doG3) {                       // G3 full-K + epilogue, tile 2(j-2)+g
        // A=w3f, B=h2frag: D[ch][px], lane=px(c16), regs=4 consecutive ch
        const short* srch2 = sH2 + (((j - 1) & 1) * 2 + g) * 2176;
        __builtin_amdgcn_s_setprio(1);
#pragma unroll
        for (int kc = 0; kc < 4; ++kc) {
          short8 a = *(const short8*)(srch2 + c16 * 136 + kc * 32 + q8);
          acc3 = MFMA16(w3f[kc], a, acc3);
        }
        __builtin_amdgcn_s_setprio(0);
        float4v vv;
#pragma unroll
        for (int r = 0; r < 4; ++r) vv[r] = fminf(fmaxf(acc3[r], 0.f), 1.f);
        if (LAST) {
#pragma unroll
          for (int r = 0; r < 4; ++r)
            dout[((size_t)(b * 16 + q * 4 + r) * 224 + hglob3) * 224 + cb3 + c16] = vv[r];
        } else {
          const size_t pix = (size_t)(b * 224 + hglob3) * 224 + cb3 + c16;
          *(float4v*)(xd32 + pix * 16 + q * 4) = vv;          // 1x b128
          *(uint2v*)(xd16 + pix * 16 + q * 4) =               // 1x b64
              (uint2v){pk2bf(vv[0], vv[1]), pk2bf(vv[2], vv[3])};
        }
      }
      sync_lds();
    }
  }
}

// ---------------------------------------------------------------------------
extern "C" void kernel_launch(void* const* d_in, const int* in_sizes, int n_in,
                              void* d_out, int out_size, void* d_ws, size_t ws_size,
                              hipStream_t stream) {
  const float* x  = (const float*)d_in[0];
  const float* wp = (const float*)d_in[1];
  const float* w1 = (const float*)d_in[2];
  const float* b1 = (const float*)d_in[3];
  const float* w2 = (const float*)d_in[4];
  const float* b2 = (const float*)d_in[5];
  const float* w3 = (const float*)d_in[6];

  char* ws = (char*)d_ws;
  short* wEg = (short*)(ws + WS_WE);
  short* w2g = (short*)(ws + WS_W2);
  short* w3g = (short*)(ws + WS_W3);
  float* b1p = (float*)(ws + WS_B1);
  float* b2p = (float*)(ws + WS_B2);
  float* X32[2] = {(float*)(ws + WS_X32A), (float*)(ws + WS_X32B)};
  short* X16[2] = {(short*)(ws + WS_X16A), (short*)(ws + WS_X16B)};

  prep_x<<<12544, 256, 0, stream>>>(x, X32[0], X16[0]);
  prep_w<<<163, 256, 0, stream>>>(wp, w1, b1, w2, b2, w3, wEg, w2g, w3g, b1p, b2p);

  for (int s = 0; s < 39; ++s) {
    int sb = s & 1;
    ca_step<false><<<448, 512, 0, stream>>>(wEg, w2g, w3g, b1p, b2p,
                                            X32[sb], X16[sb],
                                            X32[1 - sb], X16[1 - sb], nullptr);
  }
  ca_step<true><<<448, 512, 0, stream>>>(wEg, w2g, w3g, b1p, b2p,
                                         X32[1], X16[1],
                                         X32[0], X16[0], (float*)d_out);
}

// Round 7
// 1009.024 us; speedup vs baseline: 1.2565x; 1.0091x over previous
//
#include <hip/hip_runtime.h>

// ---------------------------------------------------------------------------
// NeuralCA fused step, multi-launch, 4 waves/SIMD:
//   512-thread blocks (8 waves), 2-row blocks, 448 blocks, 2 blocks/CU
//   (63.7 KB LDS), __launch_bounds__(512,4) -> VGPR cap 128/wave.
//   waves 0-3 (G1, quarter wq): h1 chans 32wq..32wq+31 of tiles {2j,2j+1}
//   waves 4-7 (G23, quarter g): G2 chans 32g..+31 of tiles {2(j-1),2(j-1)+1};
//        waves g<2 also: G3 full-K + epilogue of tile 2(j-2)+g
//   h1/h2 via double-buffered LDS mailboxes, 1 lgkm-only barrier per iter.
//
//   R14 (on R11 champion; R13 rebalance+swizzle REVERTED, +3%):
//   G1 REGISTER PREFETCH ACROSS THE BARRIER. sXH is static after the
//   prologue sync, so G1 prefetches iter j+1's 10 B-frags (pa/pb, 40 VGPR)
//   right after its MFMA phase; read latency hides under the epilogue VALU
//   and the barrier drain. Post-barrier, G1 starts MFMAs with ZERO LDS
//   reads -> removes ~half of the post-barrier LDS read burst (~160 b128/CU
//   -> ~80) which the evidence chain (R8+4%,R9 0%,R11 -2%,R12 +28%,R13 +3%)
//   identifies as the remaining critical-path cost at the sync point.
//   G1 VGPR ~120 < 128 cap (R8 ran a similar count without demotion).
// ---------------------------------------------------------------------------

typedef __attribute__((ext_vector_type(8))) short short8;
typedef __attribute__((ext_vector_type(4))) float float4v;
typedef __attribute__((ext_vector_type(2))) unsigned int uint2v;

#define MFMA16(a, b, c) __builtin_amdgcn_mfma_f32_16x16x32_bf16((a), (b), (c), 0, 0, 0)

__device__ __forceinline__ short f2bf(float f) {
  unsigned u = __builtin_bit_cast(unsigned, f);
  return (short)((u + 0x8000u) >> 16);     // round-half-up
}

__device__ __forceinline__ unsigned pk2bf(float a, float b) {
#if __has_builtin(__builtin_amdgcn_cvt_pk_bf16_f32)
  typedef __attribute__((ext_vector_type(2))) __bf16 bf2;
  bf2 r = __builtin_amdgcn_cvt_pk_bf16_f32(a, b);
  return __builtin_bit_cast(unsigned, r);
#else
  unsigned ua = __builtin_bit_cast(unsigned, a), ub = __builtin_bit_cast(unsigned, b);
  return ((ua + 0x8000u) >> 16) | (((ub + 0x8000u) >> 16) << 16);
#endif
}

__device__ __forceinline__ void async16(const void* g, void* l) {
  __builtin_amdgcn_global_load_lds((const __attribute__((address_space(1))) void*)g,
                                   (__attribute__((address_space(3))) void*)l,
                                   16, 0, 0);
}

// LDS-only barrier (no vmcnt drain - global stores fly free)
__device__ __forceinline__ void sync_lds() {
  asm volatile("s_waitcnt lgkmcnt(0)\n\ts_barrier" ::: "memory");
}

// ---- workspace layout (bytes) ----
#define WS_WE    0          // W_eff^T [128][168] bf16 (K pad 144->168, zeros)
#define WS_W2    43008      // W2      [128][136] bf16 (K identity, pad 136)
#define WS_W3    77824      // W3      [ 16][136] bf16 (identity, pad 2560)
#define WS_B1    82944      // b1 f32 [128] (identity)
#define WS_B2    83456      // b2 f32 [128] (identity)
#define WS_X32A  83968
#define WS_X32B  12929024
#define WS_X16A  25774080
#define WS_X16B  32196608

// ---------------------------------------------------------------------------
__global__ void prep_x(const float* __restrict__ x, float* __restrict__ x32,
                       short* __restrict__ x16) {
  int i = blockIdx.x * 256 + threadIdx.x;          // exactly 3211264 threads
  int w = i % 224;
  int h = (i / 224) % 224;
  int c = (i / 50176) & 15;
  int bb = i / 802816;
  float v = x[i];
  int o = ((bb * 224 + h) * 224 + w) * 16 + c;     // NHWC
  x32[o] = v;
  x16[o] = f2bf(v);
}

// identity layouts (operand-swapped mailboxes store chpos == channel)
__global__ void prep_w(const float* __restrict__ wp, const float* __restrict__ w1,
                       const float* __restrict__ b1, const float* __restrict__ w2,
                       const float* __restrict__ b2, const float* __restrict__ w3,
                       short* __restrict__ wE, short* __restrict__ w2t,
                       short* __restrict__ w3t, float* __restrict__ b1p,
                       float* __restrict__ b2p) {
  int i = blockIdx.x * 256 + threadIdx.x;          // exactly 41728 threads
  if (i < 21504) {                                  // W_eff [o=128][k=168]
    int o = i / 168, k = i % 168;
    float v = 0.f;
    if (k < 144) {
      int off = k >> 4, c = k & 15;                 // k = offset*16 + c
      for (int c3 = 0; c3 < 48; ++c3)
        v += w1[o * 48 + c3] * wp[c3 * 144 + c * 9 + off];
    }
    wE[i] = f2bf(v);
  } else if (i < 38912) {                           // W2 [n=128][kk=136]
    int j = i - 21504;
    int n = j / 136, kk = j % 136;
    w2t[j] = (kk < 128) ? f2bf(w2[n * 128 + kk]) : (short)0;
  } else if (i < 41472) {                           // W3 [16][136], pad 2560
    int j = i - 38912;
    float v = 0.f;
    if (j < 2176) {
      int n = j / 136, kk = j % 136;
      if (kk < 128) v = w3[n * 128 + kk];
    }
    w3t[j] = f2bf(v);
  } else if (i < 41600) {
    int p = i - 41472;
    b1p[p] = b1[p];
  } else {
    int p = i - 41600;
    b2p[p] = b2[p];
  }
}

// ---------------------------------------------------------------------------
// One CA step. Block = 2 image rows, 512 threads = 8 waves. 28 tiles of
// 16 px; pipeline over 16 iterations:
//   G1 wave wq:  iter j<14:     chan-quarter of h1, tiles {2j,2j+1} -> sBUF j&1
//   G23 wave g:  iter 1<=j<=14: chan-quarter of h2, tiles {2(j-1),..} -> sH2 j&1
//   G23 g<2:     iter j>=2:     G3 full-K + epilogue, tile 2(j-2)+g
template <bool LAST>
__global__ __launch_bounds__(512, 4) void ca_step(
    const short* __restrict__ wEg, const short* __restrict__ w2g,
    const short* __restrict__ w3g, const float* __restrict__ b1p,
    const float* __restrict__ b2p, const float* __restrict__ xs32,
    const short* __restrict__ xs16, float* __restrict__ xd32,
    short* __restrict__ xd16, float* __restrict__ dout) {
  __shared__ short sXH[4 * 3616];       // 28928 B  halo: 4 rows x 226 x 16ch
  __shared__ short sBUF[2 * 2 * 2176];  // 17408 B  h1 mailbox dbuf x 2 tiles
  __shared__ short sH2[2 * 2 * 2176];   // 17408 B  h2 dbuf x 2 tiles
  // total 63744 B -> 2 blocks/CU, 16 waves/CU = 4 waves/SIMD

  const int tid = threadIdx.x;
  const int lane = tid & 63;
  const int wv = tid >> 6;              // 0..7
  const int c16 = lane & 15;
  const int q = lane >> 4;
  const int q8 = q * 8;
  const int qh = q >> 1;
  const int c0 = (q & 1) * 8;

  const int blk = blockIdx.x;           // 448 = 4 batches x 112 rowgroups
  const int b = blk / 112;
  const int h0 = (blk % 112) * 2;

  // ---- stage halo: 4 rows x 7 chunks (1KB each); OOB rows -> zeros ----
  const short8 z8 = {0, 0, 0, 0, 0, 0, 0, 0};
  for (int t = wv; t < 28; t += 8) {
    int hr = t / 7, ck = t % 7;
    int hh = h0 - 1 + hr;
    char* l = (char*)sXH + hr * 7232 + 32 + ck * 1024;  // col 0 = image col -1
    if (hh >= 0 && hh < 224) {
      const char* g = (const char*)xs16 + ((size_t)(b * 224 + hh) * 224) * 32 + ck * 1024;
      async16(g + lane * 16, l);
    } else {
      *(short8*)(l + lane * 16) = z8;
    }
  }
  if (tid < 16) {   // zero edge columns (image col -1 and 224) for all 4 rows
    int hr = tid >> 2, wch = tid & 3;
    int colb = (wch < 2) ? 0 : 225;
    *(short8*)((char*)sXH + hr * 7232 + colb * 32 + (wch & 1) * 16) = z8;
  }

  if (wv < 4) {
    // ====== G1 role, chan-quarter wq: conv3x3+MLP1 fused (A=W, B=x) ======
    const int wq = wv;
    const int obase = 32 * wq;          // channel rows 32wq..32wq+31
    short8 wf[5][2];                    // 40 VGPR; A-frag: row obase+16n+c16
#pragma unroll
    for (int kc = 0; kc < 5; ++kc)
#pragma unroll
      for (int n = 0; n < 2; ++n)
        wf[kc][n] = *(const short8*)(wEg + (obase + 16 * n + c16) * 168 + kc * 32 + q8);
    float4v bH[2];                      // bias for chans obase+16n+4q..+3
#pragma unroll
    for (int n = 0; n < 2; ++n)
      bH[n] = *(const float4v*)(b1p + obase + 16 * n + 4 * q);

    // per-lane im2col fragment offsets (loop-invariant, 5 scalars)
    int aoff[5];
#pragma unroll
    for (int kc = 0; kc < 5; ++kc) {
      int off = kc * 2 + qh;
      if (off > 8) off = 8;             // K 144..159 hit zero rows of W_eff
      int dy = (off * 11) >> 5;         // off/3
      int dxx = off - dy * 3;
      aoff[kc] = (dy * 226 + dxx + c16) * 16 + c0;
    }

    __syncthreads();                    // halo ready (drains vmcnt)

    // prefetch iter 0's fragments (sXH static -> safe any time)
    short8 pa[5], pb[5];                // 40 VGPR
    {
      const int hb0 = 0 * 16, hb1 = 16 * 16;  // tiles 0,1 (row 0)
#pragma unroll
      for (int kc = 0; kc < 5; ++kc) {
        pa[kc] = *(const short8*)(sXH + hb0 + aoff[kc]);
        pb[kc] = *(const short8*)(sXH + hb1 + aoff[kc]);
      }
    }

    for (int j = 0; j < 16; ++j) {
      if (j < 14) {
        float4v acc[2][2];
#pragma unroll
        for (int tt = 0; tt < 2; ++tt)
#pragma unroll
          for (int n = 0; n < 2; ++n) acc[tt][n] = (float4v){0.f, 0.f, 0.f, 0.f};
        __builtin_amdgcn_s_setprio(1);
#pragma unroll
        for (int kc = 0; kc < 5; ++kc) {
#pragma unroll
          for (int n = 0; n < 2; ++n) {
            acc[0][n] = MFMA16(wf[kc][n], pa[kc], acc[0][n]);
            acc[1][n] = MFMA16(wf[kc][n], pb[kc], acc[1][n]);
          }
        }
        __builtin_amdgcn_s_setprio(0);
        // prefetch j+1's fragments; latency hides under epilogue + drain
        if (j + 1 < 14) {
          const int t0 = 2 * (j + 1), t1 = t0 + 1;
          const int hb0 = ((t0 / 14) * 226 + (t0 % 14) * 16) * 16;
          const int hb1 = ((t1 / 14) * 226 + (t1 % 14) * 16) * 16;
#pragma unroll
          for (int kc = 0; kc < 5; ++kc) {
            pa[kc] = *(const short8*)(sXH + hb0 + aoff[kc]);
            pb[kc] = *(const short8*)(sXH + hb1 + aoff[kc]);
          }
        }
        // D[ch][px]: lane=px(c16), regs=4 consecutive ch -> b64 writes
#pragma unroll
        for (int tt = 0; tt < 2; ++tt) {
          short* dst = sBUF + ((j & 1) * 2 + tt) * 2176 + c16 * 136;
#pragma unroll
          for (int n = 0; n < 2; ++n) {
            unsigned d0 = pk2bf(fmaxf(acc[tt][n][0] + bH[n][0], 0.f),
                                fmaxf(acc[tt][n][1] + bH[n][1], 0.f));
            unsigned d1 = pk2bf(fmaxf(acc[tt][n][2] + bH[n][2], 0.f),
                                fmaxf(acc[tt][n][3] + bH[n][3], 0.f));
            *(uint2v*)(dst + obase + 16 * n + 4 * q) = (uint2v){d0, d1};
          }
        }
      }
      sync_lds();
    }
  } else {
    // ====== G23 role, chan-quarter g: MLP2 (A=W2, B=h1) + (g<2) MLP3 =====
    const int g = wv - 4;
    const int obase = 32 * g;
    short8 w2f[4][2];                   // 32 VGPR; A-frag row obase+16n+c16
    short8 w3f[4];                      // 16 VGPR
#pragma unroll
    for (int kc = 0; kc < 4; ++kc)
#pragma unroll
      for (int n = 0; n < 2; ++n)
        w2f[kc][n] = *(const short8*)(w2g + (obase + 16 * n + c16) * 136 + kc * 32 + q8);
#pragma unroll
    for (int kc = 0; kc < 4; ++kc)
      w3f[kc] = *(const short8*)(w3g + c16 * 136 + kc * 32 + q8);
    float4v bG[2];
#pragma unroll
    for (int n = 0; n < 2; ++n)
      bG[n] = *(const float4v*)(b2p + obase + 16 * n + 4 * q);

    __syncthreads();                    // halo ready

    for (int j = 0; j < 16; ++j) {
      float4v acc3;
      int cb3 = 0, hglob3 = 0;
      const bool doG3 = (g < 2) && (j >= 2);
      if (doG3) {                       // residual (b128) -> MFMA C-in
        const int t3 = 2 * (j - 2) + g;
        cb3 = (t3 % 14) * 16; hglob3 = h0 + t3 / 14;
        const size_t pix = (size_t)(b * 224 + hglob3) * 224 + cb3 + c16;
        acc3 = *(const float4v*)(xs32 + pix * 16 + q * 4);
      }
      if (j >= 1 && j <= 14) {          // G2 quarter on tiles 2(j-1), 2(j-1)+1
        const short* srcA = sBUF + (((j - 1) & 1) * 2 + 0) * 2176;
        const short* srcB = sBUF + (((j - 1) & 1) * 2 + 1) * 2176;
        float4v acc2[2][2];
#pragma unroll
        for (int tt = 0; tt < 2; ++tt)
#pragma unroll
          for (int n = 0; n < 2; ++n) acc2[tt][n] = (float4v){0.f, 0.f, 0.f, 0.f};
        __builtin_amdgcn_s_setprio(1);
#pragma unroll
        for (int kc = 0; kc < 4; ++kc) {
          short8 aA = *(const short8*)(srcA + c16 * 136 + kc * 32 + q8);  // B-frag
          short8 aB = *(const short8*)(srcB + c16 * 136 + kc * 32 + q8);
#pragma unroll
          for (int n = 0; n < 2; ++n) {
            acc2[0][n] = MFMA16(w2f[kc][n], aA, acc2[0][n]);
            acc2[1][n] = MFMA16(w2f[kc][n], aB, acc2[1][n]);
          }
        }
        __builtin_amdgcn_s_setprio(0);
        // D[ch2][px] -> b64 writes, conflict-free
#pragma unroll
        for (int tt = 0; tt < 2; ++tt) {
          short* dsth2 = sH2 + ((j & 1) * 2 + tt) * 2176 + c16 * 136;
#pragma unroll
          for (int n = 0; n < 2; ++n) {
            unsigned d0 = pk2bf(fmaxf(acc2[tt][n][0] + bG[n][0], 0.f),
                                fmaxf(acc2[tt][n][1] + bG[n][1], 0.f));
            unsigned d1 = pk2bf(fmaxf(acc2[tt][n][2] + bG[n][2], 0.f),
                                fmaxf(acc2[tt][n][3] + bG[n][3], 0.f));
            *(uint2v*)(dsth2 + obase + 16 * n + 4 * q) = (uint2v){d0, d1};
          }
        }
      }
      if (doG3) {                       // G3 full-K + epilogue, tile 2(j-2)+g
        // A=w3f, B=h2frag: D[ch][px], lane=px(c16), regs=4 consecutive ch
        const short* srch2 = sH2 + (((j - 1) & 1) * 2 + g) * 2176;
        __builtin_amdgcn_s_setprio(1);
#pragma unroll
        for (int kc = 0; kc < 4; ++kc) {
          short8 a = *(const short8*)(srch2 + c16 * 136 + kc * 32 + q8);
          acc3 = MFMA16(w3f[kc], a, acc3);
        }
        __builtin_amdgcn_s_setprio(0);
        float4v vv;
#pragma unroll
        for (int r = 0; r < 4; ++r) vv[r] = fminf(fmaxf(acc3[r], 0.f), 1.f);
        if (LAST) {
#pragma unroll
          for (int r = 0; r < 4; ++r)
            dout[((size_t)(b * 16 + q * 4 + r) * 224 + hglob3) * 224 + cb3 + c16] = vv[r];
        } else {
          const size_t pix = (size_t)(b * 224 + hglob3) * 224 + cb3 + c16;
          *(float4v*)(xd32 + pix * 16 + q * 4) = vv;          // 1x b128
          *(uint2v*)(xd16 + pix * 16 + q * 4) =               // 1x b64
              (uint2v){pk2bf(vv[0], vv[1]), pk2bf(vv[2], vv[3])};
        }
      }
      sync_lds();
    }
  }
}

// ---------------------------------------------------------------------------
extern "C" void kernel_launch(void* const* d_in, const int* in_sizes, int n_in,
                              void* d_out, int out_size, void* d_ws, size_t ws_size,
                              hipStream_t stream) {
  const float* x  = (const float*)d_in[0];
  const float* wp = (const float*)d_in[1];
  const float* w1 = (const float*)d_in[2];
  const float* b1 = (const float*)d_in[3];
  const float* w2 = (const float*)d_in[4];
  const float* b2 = (const float*)d_in[5];
  const float* w3 = (const float*)d_in[6];

  char* ws = (char*)d_ws;
  short* wEg = (short*)(ws + WS_WE);
  short* w2g = (short*)(ws + WS_W2);
  short* w3g = (short*)(ws + WS_W3);
  float* b1p = (float*)(ws + WS_B1);
  float* b2p = (float*)(ws + WS_B2);
  float* X32[2] = {(float*)(ws + WS_X32A), (float*)(ws + WS_X32B)};
  short* X16[2] = {(short*)(ws + WS_X16A), (short*)(ws + WS_X16B)};

  prep_x<<<12544, 256, 0, stream>>>(x, X32[0], X16[0]);
  prep_w<<<163, 256, 0, stream>>>(wp, w1, b1, w2, b2, w3, wEg, w2g, w3g, b1p, b2p);

  for (int s = 0; s < 39; ++s) {
    int sb = s & 1;
    ca_step<false><<<448, 512, 0, stream>>>(wEg, w2g, w3g, b1p, b2p,
                                            X32[sb], X16[sb],
                                            X32[1 - sb], X16[1 - sb], nullptr);
  }
  ca_step<true><<<448, 512, 0, stream>>>(wEg, w2g, w3g, b1p, b2p,
                                         X32[1], X16[1],
                                         X32[0], X16[0], (float*)d_out);
}

// Round 8
// 960.827 us; speedup vs baseline: 1.3195x; 1.0502x over previous
//
#include <hip/hip_runtime.h>

// ---------------------------------------------------------------------------
// NeuralCA fused step, multi-launch, 4 waves/SIMD:
//   512-thread blocks (8 waves), 2-row blocks, 448 blocks, 2 blocks/CU
//   (63.7 KB LDS), __launch_bounds__(512,4) -> VGPR cap 128/wave.
//   waves 0-3 (G1, quarter wq): h1 chans 32wq..32wq+31 of tiles {2j,2j+1}
//   waves 4-7 (G23, quarter g): G2 chans 32g..+31 of tiles {2(j-1),2(j-1)+1};
//        waves g<2 also: G3 full-K + epilogue of tile 2(j-2)+g
//   h1/h2 via double-buffered LDS mailboxes, 1 lgkm-only barrier per iter.
//
//   R15 = R11 champion + XCD-BIJECTIVE SWIZZLE ONLY (single-variable A/B;
//   R14 prefetch REVERTED +2.4%, R13's rebalance suspected for its +3%).
//   Swizzle mechanism: 448 = 8 XCDs x 56; blockIdx&7 = XCD under round-robin
//   dispatch, x56 gives each XCD a contiguous half-batch band. Step-s x16/x32
//   writes for a band (~4.8 MB) land in that XCD's L2; step-s+1's halo
//   staging + residual loads for the same band re-read them L2-local
//   (~200 cyc) instead of cross-XCD L3/HBM (~400-900 cyc). Shortens the
//   per-launch prologue vmcnt drain and G3's residual-load latency.
//   Evidence ledger: R8 +4%, R9 0%, R11 -2% (champion), R12 +28%, R13 +3%,
//   R14 +2.4% -> iteration structure is locally optimal; only cross-launch
//   locality remains unprobed in isolation.
// ---------------------------------------------------------------------------

typedef __attribute__((ext_vector_type(8))) short short8;
typedef __attribute__((ext_vector_type(4))) float float4v;
typedef __attribute__((ext_vector_type(2))) unsigned int uint2v;

#define MFMA16(a, b, c) __builtin_amdgcn_mfma_f32_16x16x32_bf16((a), (b), (c), 0, 0, 0)

__device__ __forceinline__ short f2bf(float f) {
  unsigned u = __builtin_bit_cast(unsigned, f);
  return (short)((u + 0x8000u) >> 16);     // round-half-up
}

__device__ __forceinline__ unsigned pk2bf(float a, float b) {
#if __has_builtin(__builtin_amdgcn_cvt_pk_bf16_f32)
  typedef __attribute__((ext_vector_type(2))) __bf16 bf2;
  bf2 r = __builtin_amdgcn_cvt_pk_bf16_f32(a, b);
  return __builtin_bit_cast(unsigned, r);
#else
  unsigned ua = __builtin_bit_cast(unsigned, a), ub = __builtin_bit_cast(unsigned, b);
  return ((ua + 0x8000u) >> 16) | (((ub + 0x8000u) >> 16) << 16);
#endif
}

__device__ __forceinline__ void async16(const void* g, void* l) {
  __builtin_amdgcn_global_load_lds((const __attribute__((address_space(1))) void*)g,
                                   (__attribute__((address_space(3))) void*)l,
                                   16, 0, 0);
}

// LDS-only barrier (no vmcnt drain - global stores fly free)
__device__ __forceinline__ void sync_lds() {
  asm volatile("s_waitcnt lgkmcnt(0)\n\ts_barrier" ::: "memory");
}

// ---- workspace layout (bytes) ----
#define WS_WE    0          // W_eff^T [128][168] bf16 (K pad 144->168, zeros)
#define WS_W2    43008      // W2      [128][136] bf16 (K identity, pad 136)
#define WS_W3    77824      // W3      [ 16][136] bf16 (identity, pad 2560)
#define WS_B1    82944      // b1 f32 [128] (identity)
#define WS_B2    83456      // b2 f32 [128] (identity)
#define WS_X32A  83968
#define WS_X32B  12929024
#define WS_X16A  25774080
#define WS_X16B  32196608

// ---------------------------------------------------------------------------
__global__ void prep_x(const float* __restrict__ x, float* __restrict__ x32,
                       short* __restrict__ x16) {
  int i = blockIdx.x * 256 + threadIdx.x;          // exactly 3211264 threads
  int w = i % 224;
  int h = (i / 224) % 224;
  int c = (i / 50176) & 15;
  int bb = i / 802816;
  float v = x[i];
  int o = ((bb * 224 + h) * 224 + w) * 16 + c;     // NHWC
  x32[o] = v;
  x16[o] = f2bf(v);
}

// identity layouts (operand-swapped mailboxes store chpos == channel)
__global__ void prep_w(const float* __restrict__ wp, const float* __restrict__ w1,
                       const float* __restrict__ b1, const float* __restrict__ w2,
                       const float* __restrict__ b2, const float* __restrict__ w3,
                       short* __restrict__ wE, short* __restrict__ w2t,
                       short* __restrict__ w3t, float* __restrict__ b1p,
                       float* __restrict__ b2p) {
  int i = blockIdx.x * 256 + threadIdx.x;          // exactly 41728 threads
  if (i < 21504) {                                  // W_eff [o=128][k=168]
    int o = i / 168, k = i % 168;
    float v = 0.f;
    if (k < 144) {
      int off = k >> 4, c = k & 15;                 // k = offset*16 + c
      for (int c3 = 0; c3 < 48; ++c3)
        v += w1[o * 48 + c3] * wp[c3 * 144 + c * 9 + off];
    }
    wE[i] = f2bf(v);
  } else if (i < 38912) {                           // W2 [n=128][kk=136]
    int j = i - 21504;
    int n = j / 136, kk = j % 136;
    w2t[j] = (kk < 128) ? f2bf(w2[n * 128 + kk]) : (short)0;
  } else if (i < 41472) {                           // W3 [16][136], pad 2560
    int j = i - 38912;
    float v = 0.f;
    if (j < 2176) {
      int n = j / 136, kk = j % 136;
      if (kk < 128) v = w3[n * 128 + kk];
    }
    w3t[j] = f2bf(v);
  } else if (i < 41600) {
    int p = i - 41472;
    b1p[p] = b1[p];
  } else {
    int p = i - 41600;
    b2p[p] = b2[p];
  }
}

// ---------------------------------------------------------------------------
// One CA step. Block = 2 image rows, 512 threads = 8 waves. 28 tiles of
// 16 px; pipeline over 16 iterations:
//   G1 wave wq:  iter j<14:     chan-quarter of h1, tiles {2j,2j+1} -> sBUF j&1
//   G23 wave g:  iter 1<=j<=14: chan-quarter of h2, tiles {2(j-1),..} -> sH2 j&1
//   G23 g<2:     iter j>=2:     G3 full-K + epilogue, tile 2(j-2)+g
template <bool LAST>
__global__ __launch_bounds__(512, 4) void ca_step(
    const short* __restrict__ wEg, const short* __restrict__ w2g,
    const short* __restrict__ w3g, const float* __restrict__ b1p,
    const float* __restrict__ b2p, const float* __restrict__ xs32,
    const short* __restrict__ xs16, float* __restrict__ xd32,
    short* __restrict__ xd16, float* __restrict__ dout) {
  __shared__ short sXH[4 * 3616];       // 28928 B  halo: 4 rows x 226 x 16ch
  __shared__ short sBUF[2 * 2 * 2176];  // 17408 B  h1 mailbox dbuf x 2 tiles
  __shared__ short sH2[2 * 2 * 2176];   // 17408 B  h2 dbuf x 2 tiles
  // total 63744 B -> 2 blocks/CU, 16 waves/CU = 4 waves/SIMD

  const int tid = threadIdx.x;
  const int lane = tid & 63;
  const int wv = tid >> 6;              // 0..7
  const int c16 = lane & 15;
  const int q = lane >> 4;
  const int q8 = q * 8;
  const int qh = q >> 1;
  const int c0 = (q & 1) * 8;

  // XCD-bijective swizzle: 448 = 8 XCDs x 56. blockIdx&7 = XCD (round-robin
  // dispatch); x56 -> each XCD owns a contiguous half-batch band across all
  // 40 launches, so step-s state writes are step-s+1 L2-local reads.
  const int blk = (blockIdx.x & 7) * 56 + (blockIdx.x >> 3);
  const int b = blk / 112;              // 4 batches x 112 rowgroups
  const int h0 = (blk % 112) * 2;

  // ---- stage halo: 4 rows x 7 chunks (1KB each); OOB rows -> zeros ----
  const short8 z8 = {0, 0, 0, 0, 0, 0, 0, 0};
  for (int t = wv; t < 28; t += 8) {
    int hr = t / 7, ck = t % 7;
    int hh = h0 - 1 + hr;
    char* l = (char*)sXH + hr * 7232 + 32 + ck * 1024;  // col 0 = image col -1
    if (hh >= 0 && hh < 224) {
      const char* g = (const char*)xs16 + ((size_t)(b * 224 + hh) * 224) * 32 + ck * 1024;
      async16(g + lane * 16, l);
    } else {
      *(short8*)(l + lane * 16) = z8;
    }
  }
  if (tid < 16) {   // zero edge columns (image col -1 and 224) for all 4 rows
    int hr = tid >> 2, wch = tid & 3;
    int colb = (wch < 2) ? 0 : 225;
    *(short8*)((char*)sXH + hr * 7232 + colb * 32 + (wch & 1) * 16) = z8;
  }

  if (wv < 4) {
    // ====== G1 role, chan-quarter wq: conv3x3+MLP1 fused (A=W, B=x) ======
    const int wq = wv;
    const int obase = 32 * wq;          // channel rows 32wq..32wq+31
    short8 wf[5][2];                    // 40 VGPR; A-frag: row obase+16n+c16
#pragma unroll
    for (int kc = 0; kc < 5; ++kc)
#pragma unroll
      for (int n = 0; n < 2; ++n)
        wf[kc][n] = *(const short8*)(wEg + (obase + 16 * n + c16) * 168 + kc * 32 + q8);
    float4v bH[2];                      // bias for chans obase+16n+4q..+3
#pragma unroll
    for (int n = 0; n < 2; ++n)
      bH[n] = *(const float4v*)(b1p + obase + 16 * n + 4 * q);

    __syncthreads();                    // halo ready (drains vmcnt)

    for (int j = 0; j < 16; ++j) {
      if (j < 14) {
        const int t0 = 2 * j, t1 = t0 + 1;
        const int hb0 = ((t0 / 14) * 226 + (t0 % 14) * 16) * 16;
        const int hb1 = ((t1 / 14) * 226 + (t1 % 14) * 16) * 16;
        float4v acc[2][2];
#pragma unroll
        for (int tt = 0; tt < 2; ++tt)
#pragma unroll
          for (int n = 0; n < 2; ++n) acc[tt][n] = (float4v){0.f, 0.f, 0.f, 0.f};
        __builtin_amdgcn_s_setprio(1);
#pragma unroll
        for (int kc = 0; kc < 5; ++kc) {
          int off = kc * 2 + qh;
          if (off > 8) off = 8;         // K 144..159 hit zero rows of W_eff
          int dy = (off * 11) >> 5;     // off/3
          int dxx = off - dy * 3;
          const int ao = (dy * 226 + dxx + c16) * 16 + c0;
          short8 a0 = *(const short8*)(sXH + hb0 + ao);   // B-frag, same addr
          short8 a1 = *(const short8*)(sXH + hb1 + ao);
#pragma unroll
          for (int n = 0; n < 2; ++n) {
            acc[0][n] = MFMA16(wf[kc][n], a0, acc[0][n]);
            acc[1][n] = MFMA16(wf[kc][n], a1, acc[1][n]);
          }
        }
        __builtin_amdgcn_s_setprio(0);
        // D[ch][px]: lane=px(c16), regs=4 consecutive ch -> b64 writes
#pragma unroll
        for (int tt = 0; tt < 2; ++tt) {
          short* dst = sBUF + ((j & 1) * 2 + tt) * 2176 + c16 * 136;
#pragma unroll
          for (int n = 0; n < 2; ++n) {
            unsigned d0 = pk2bf(fmaxf(acc[tt][n][0] + bH[n][0], 0.f),
                                fmaxf(acc[tt][n][1] + bH[n][1], 0.f));
            unsigned d1 = pk2bf(fmaxf(acc[tt][n][2] + bH[n][2], 0.f),
                                fmaxf(acc[tt][n][3] + bH[n][3], 0.f));
            *(uint2v*)(dst + obase + 16 * n + 4 * q) = (uint2v){d0, d1};
          }
        }
      }
      sync_lds();
    }
  } else {
    // ====== G23 role, chan-quarter g: MLP2 (A=W2, B=h1) + (g<2) MLP3 =====
    const int g = wv - 4;
    const int obase = 32 * g;
    short8 w2f[4][2];                   // 32 VGPR; A-frag row obase+16n+c16
    short8 w3f[4];                      // 16 VGPR
#pragma unroll
    for (int kc = 0; kc < 4; ++kc)
#pragma unroll
      for (int n = 0; n < 2; ++n)
        w2f[kc][n] = *(const short8*)(w2g + (obase + 16 * n + c16) * 136 + kc * 32 + q8);
#pragma unroll
    for (int kc = 0; kc < 4; ++kc)
      w3f[kc] = *(const short8*)(w3g + c16 * 136 + kc * 32 + q8);
    float4v bG[2];
#pragma unroll
    for (int n = 0; n < 2; ++n)
      bG[n] = *(const float4v*)(b2p + obase + 16 * n + 4 * q);

    __syncthreads();                    // halo ready

    for (int j = 0; j < 16; ++j) {
      float4v acc3;
      int cb3 = 0, hglob3 = 0;
      const bool doG3 = (g < 2) && (j >= 2);
      if (doG3) {                       // residual (b128) -> MFMA C-in
        const int t3 = 2 * (j - 2) + g;
        cb3 = (t3 % 14) * 16; hglob3 = h0 + t3 / 14;
        const size_t pix = (size_t)(b * 224 + hglob3) * 224 + cb3 + c16;
        acc3 = *(const float4v*)(xs32 + pix * 16 + q * 4);
      }
      if (j >= 1 && j <= 14) {          // G2 quarter on tiles 2(j-1), 2(j-1)+1
        const short* srcA = sBUF + (((j - 1) & 1) * 2 + 0) * 2176;
        const short* srcB = sBUF + (((j - 1) & 1) * 2 + 1) * 2176;
        float4v acc2[2][2];
#pragma unroll
        for (int tt = 0; tt < 2; ++tt)
#pragma unroll
          for (int n = 0; n < 2; ++n) acc2[tt][n] = (float4v){0.f, 0.f, 0.f, 0.f};
        __builtin_amdgcn_s_setprio(1);
#pragma unroll
        for (int kc = 0; kc < 4; ++kc) {
          short8 aA = *(const short8*)(srcA + c16 * 136 + kc * 32 + q8);  // B-frag
          short8 aB = *(const short8*)(srcB + c16 * 136 + kc * 32 + q8);
#pragma unroll
          for (int n = 0; n < 2; ++n) {
            acc2[0][n] = MFMA16(w2f[kc][n], aA, acc2[0][n]);
            acc2[1][n] = MFMA16(w2f[kc][n], aB, acc2[1][n]);
          }
        }
        __builtin_amdgcn_s_setprio(0);
        // D[ch2][px] -> b64 writes, conflict-free
#pragma unroll
        for (int tt = 0; tt < 2; ++tt) {
          short* dsth2 = sH2 + ((j & 1) * 2 + tt) * 2176 + c16 * 136;
#pragma unroll
          for (int n = 0; n < 2; ++n) {
            unsigned d0 = pk2bf(fmaxf(acc2[tt][n][0] + bG[n][0], 0.f),
                                fmaxf(acc2[tt][n][1] + bG[n][1], 0.f));
            unsigned d1 = pk2bf(fmaxf(acc2[tt][n][2] + bG[n][2], 0.f),
                                fmaxf(acc2[tt][n][3] + bG[n][3], 0.f));
            *(uint2v*)(dsth2 + obase + 16 * n + 4 * q) = (uint2v){d0, d1};
          }
        }
      }
      if (doG3) {                       // G3 full-K + epilogue, tile 2(j-2)+g
        // A=w3f, B=h2frag: D[ch][px], lane=px(c16), regs=4 consecutive ch
        const short* srch2 = sH2 + (((j - 1) & 1) * 2 + g) * 2176;
        __builtin_amdgcn_s_setprio(1);
#pragma unroll
        for (int kc = 0; kc < 4; ++kc) {
          short8 a = *(const short8*)(srch2 + c16 * 136 + kc * 32 + q8);
          acc3 = MFMA16(w3f[kc], a, acc3);
        }
        __builtin_amdgcn_s_setprio(0);
        float4v vv;
#pragma unroll
        for (int r = 0; r < 4; ++r) vv[r] = fminf(fmaxf(acc3[r], 0.f), 1.f);
        if (LAST) {
#pragma unroll
          for (int r = 0; r < 4; ++r)
            dout[((size_t)(b * 16 + q * 4 + r) * 224 + hglob3) * 224 + cb3 + c16] = vv[r];
        } else {
          const size_t pix = (size_t)(b * 224 + hglob3) * 224 + cb3 + c16;
          *(float4v*)(xd32 + pix * 16 + q * 4) = vv;          // 1x b128
          *(uint2v*)(xd16 + pix * 16 + q * 4) =               // 1x b64
              (uint2v){pk2bf(vv[0], vv[1]), pk2bf(vv[2], vv[3])};
        }
      }
      sync_lds();
    }
  }
}

// ---------------------------------------------------------------------------
extern "C" void kernel_launch(void* const* d_in, const int* in_sizes, int n_in,
                              void* d_out, int out_size, void* d_ws, size_t ws_size,
                              hipStream_t stream) {
  const float* x  = (const float*)d_in[0];
  const float* wp = (const float*)d_in[1];
  const float* w1 = (const float*)d_in[2];
  const float* b1 = (const float*)d_in[3];
  const float* w2 = (const float*)d_in[4];
  const float* b2 = (const float*)d_in[5];
  const float* w3 = (const float*)d_in[6];

  char* ws = (char*)d_ws;
  short* wEg = (short*)(ws + WS_WE);
  short* w2g = (short*)(ws + WS_W2);
  short* w3g = (short*)(ws + WS_W3);
  float* b1p = (float*)(ws + WS_B1);
  float* b2p = (float*)(ws + WS_B2);
  float* X32[2] = {(float*)(ws + WS_X32A), (float*)(ws + WS_X32B)};
  short* X16[2] = {(short*)(ws + WS_X16A), (short*)(ws + WS_X16B)};

  prep_x<<<12544, 256, 0, stream>>>(x, X32[0], X16[0]);
  prep_w<<<163, 256, 0, stream>>>(wp, w1, b1, w2, b2, w3, wEg, w2g, w3g, b1p, b2p);

  for (int s = 0; s < 39; ++s) {
    int sb = s & 1;
    ca_step<false><<<448, 512, 0, stream>>>(wEg, w2g, w3g, b1p, b2p,
                                            X32[sb], X16[sb],
                                            X32[1 - sb], X16[1 - sb], nullptr);
  }
  ca_step<true><<<448, 512, 0, stream>>>(wEg, w2g, w3g, b1p, b2p,
                                         X32[1], X16[1],
                                         X32[0], X16[0], (float*)d_out);
}